// Round 6
// baseline (465.990 us; speedup 1.0000x reference)
//
#include <hip/hip_runtime.h>
#include <hip/hip_fp16.h>

#define N_NODES 100000
#define N_EDGES 1600000
#define IN_CH   128
#define NHID    64
#define OUT_CH  40
#define NBLK    391    // ceil(N_NODES/256)
#define NBUCK   196    // ceil(N_NODES/512)
#define BCAP    8960   // fixed bucket capacity (mean 8163, +8 sigma)
#define WECAP   256    // per-WAVE edge stage (8 nodes: mean 128, sigma 11.3 -> +11 sigma)

// ---------------- rowptr scans ----------------

__global__ __launch_bounds__(256) void k_scan1(const int* __restrict__ cnt,
                                               int* __restrict__ rowptr,
                                               int* __restrict__ bsum,
                                               float* __restrict__ dinv) {
    __shared__ int s[256];
    int t = threadIdx.x;
    int n = blockIdx.x * 256 + t;
    int v = (n < N_NODES) ? cnt[n] : 0;
    s[t] = v;
    __syncthreads();
    for (int off = 1; off < 256; off <<= 1) {
        int add = (t >= off) ? s[t - off] : 0;
        __syncthreads();
        s[t] += add;
        __syncthreads();
    }
    int incl = s[t];
    if (n < N_NODES) {
        rowptr[n] = incl - v;
        dinv[n] = (v > 0) ? rsqrtf((float)v) : 0.0f;
    }
    if (t == 255) bsum[blockIdx.x] = incl;
}

__global__ __launch_bounds__(512) void k_scan2(int* __restrict__ bsum) {
    __shared__ int s[512];
    int t = threadIdx.x;
    int v = (t < NBLK) ? bsum[t] : 0;
    s[t] = v;
    __syncthreads();
    for (int off = 1; off < 512; off <<= 1) {
        int add = (t >= off) ? s[t - off] : 0;
        __syncthreads();
        s[t] += add;
        __syncthreads();
    }
    if (t < NBLK) bsum[t] = s[t] - v;
}

__global__ __launch_bounds__(256) void k_scan3(const int* __restrict__ bsum,
                                               int* __restrict__ rowptr) {
    int n = blockIdx.x * 256 + threadIdx.x;
    if (n < N_NODES) rowptr[n] = rowptr[n] + bsum[n >> 8];
    if (blockIdx.x == 0 && threadIdx.x == 0) rowptr[N_NODES] = N_EDGES;
}

// ---- scatter pass A: fixed-capacity buckets by c>>9 + per-node degree (global atomics) ----

__global__ __launch_bounds__(256) void k_scatA(const int* __restrict__ ei,
                                               int* __restrict__ bucketCnt,
                                               int2* __restrict__ ebufA,
                                               int* __restrict__ cnt) {
    __shared__ int hist[NBUCK];
    __shared__ int base[NBUCK];
    int t = threadIdx.x;
    int chunk = blockIdx.x * 4096;
    for (int i = t; i < NBUCK; i += 256) hist[i] = 0;
    __syncthreads();
#pragma unroll 4
    for (int i = 0; i < 16; i++) {
        int e = chunk + i * 256 + t;
        if (e < N_EDGES) {
            int c = ei[N_EDGES + e];
            atomicAdd(&hist[c >> 9], 1);
            atomicAdd(&cnt[c], 1);          // degree count folded in (k_deg deleted)
        }
    }
    __syncthreads();
    for (int b = t; b < NBUCK; b += 256) {
        int h = hist[b];
        base[b] = h ? atomicAdd(&bucketCnt[b], h) : 0;
    }
    __syncthreads();
#pragma unroll 4
    for (int i = 0; i < 16; i++) {
        int e = chunk + i * 256 + t;
        if (e < N_EDGES) {
            int r = ei[e], c = ei[N_EDGES + e];
            int pos = atomicAdd(&base[c >> 9], 1);
            ebufA[(size_t)(c >> 9) * BCAP + pos] = make_int2(r, c);
        }
    }
}

// ---- scatter pass B: within bucket, per-NODE cursors -> CSR order (src index only) ----

__global__ __launch_bounds__(256) void k_scatB(const int2* __restrict__ ebufA,
                                               const int* __restrict__ bucketCnt,
                                               const int* __restrict__ rowptr,
                                               int* __restrict__ e4) {
    __shared__ int lcur[512];
    int b = blockIdx.x;
    int nodeB = b * 512;
    int t = threadIdx.x;
    for (int i = t; i < 512; i += 256) {
        int node = nodeB + i;
        lcur[i] = (node < N_NODES) ? rowptr[node] : 0;
    }
    __syncthreads();
    int nE = bucketCnt[b];
    const int2* src = ebufA + (size_t)b * BCAP;
    for (int i = t; i < nE; i += 256) {
        int2 rc = src[i];
        int pos = atomicAdd(&lcur[rc.y - nodeB], 1);
        e4[pos] = rc.x;
    }
}

// ---- pack 4 floats -> 4 halves (8B) ----
__device__ __forceinline__ void store_h4(__half* dst, float a, float b, float c, float d) {
    union { uint2 u; __half2 h[2]; } pk;
    pk.h[0] = __floats2half2_rn(a, b);
    pk.h[1] = __floats2half2_rn(c, d);
    *(uint2*)dst = pk.u;
}

// ---------------- fc1: h016 = fp16(relu(x @ fc1_w^T + b)); hs1 = h016*dinv ----------------

__global__ __launch_bounds__(256, 4) void k_fc1(const float* __restrict__ x,
                                                const float* __restrict__ w,
                                                const float* __restrict__ b,
                                                const float* __restrict__ dinv,
                                                __half* __restrict__ h016,
                                                __half* __restrict__ hs1) {
    __shared__ float xs[64 * 128];     // [row][f4idx ^ swz]
    int t = threadIdx.x;
    int nodeBase = blockIdx.x * 64;

    {
        int lane8 = t & 7, rhalf = t >> 3;     // 32 rows per pass
#pragma unroll
        for (int r2 = 0; r2 < 2; r2++) {
            int nl = r2 * 32 + rhalf;
            int n = nodeBase + nl;
            int swz = (nl ^ (nl >> 3)) & 7;
            float4* dstrow = (float4*)(xs + nl * 128);
            if (n < N_NODES) {
                const float4* src = (const float4*)(x + (size_t)n * IN_CH);
#pragma unroll
                for (int q = 0; q < 4; q++) dstrow[(q * 8 + lane8) ^ swz] = src[q * 8 + lane8];
            } else {
                float4 z = {0.f, 0.f, 0.f, 0.f};
#pragma unroll
                for (int q = 0; q < 4; q++) dstrow[(q * 8 + lane8) ^ swz] = z;
            }
        }
    }
    __syncthreads();

    int tx = t & 15, ty = t >> 4;
    int n0 = tx * 4, o0 = ty * 4;     // nodes on tx, outputs on ty
    int swz0 = ((n0 + 0) ^ ((n0 + 0) >> 3)) & 7;
    int swz1 = ((n0 + 1) ^ ((n0 + 1) >> 3)) & 7;
    int swz2 = ((n0 + 2) ^ ((n0 + 2) >> 3)) & 7;
    int swz3 = ((n0 + 3) ^ ((n0 + 3) >> 3)) & 7;
    const float4* xrow0 = (const float4*)(xs + (n0 + 0) * 128);
    const float4* xrow1 = (const float4*)(xs + (n0 + 1) * 128);
    const float4* xrow2 = (const float4*)(xs + (n0 + 2) * 128);
    const float4* xrow3 = (const float4*)(xs + (n0 + 3) * 128);

    float c[4][4];
#pragma unroll
    for (int i = 0; i < 4; i++)
#pragma unroll
        for (int j = 0; j < 4; j++) c[i][j] = 0.f;

#pragma unroll 4
    for (int k = 0; k < IN_CH; k += 4) {
        int kk = k >> 2;
        float4 b0 = *(const float4*)&w[(size_t)(o0 + 0) * IN_CH + k];
        float4 b1 = *(const float4*)&w[(size_t)(o0 + 1) * IN_CH + k];
        float4 b2 = *(const float4*)&w[(size_t)(o0 + 2) * IN_CH + k];
        float4 b3 = *(const float4*)&w[(size_t)(o0 + 3) * IN_CH + k];
        float4 a0 = xrow0[kk ^ swz0];
        float4 a1 = xrow1[kk ^ swz1];
        float4 a2 = xrow2[kk ^ swz2];
        float4 a3 = xrow3[kk ^ swz3];
#pragma unroll
        for (int i = 0; i < 4; i++) {
            float4 a = (i == 0) ? a0 : (i == 1) ? a1 : (i == 2) ? a2 : a3;
            c[i][0] = fmaf(a.x, b0.x, fmaf(a.y, b0.y, fmaf(a.z, b0.z, fmaf(a.w, b0.w, c[i][0]))));
            c[i][1] = fmaf(a.x, b1.x, fmaf(a.y, b1.y, fmaf(a.z, b1.z, fmaf(a.w, b1.w, c[i][1]))));
            c[i][2] = fmaf(a.x, b2.x, fmaf(a.y, b2.y, fmaf(a.z, b2.z, fmaf(a.w, b2.w, c[i][2]))));
            c[i][3] = fmaf(a.x, b3.x, fmaf(a.y, b3.y, fmaf(a.z, b3.z, fmaf(a.w, b3.w, c[i][3]))));
        }
    }

    float4 bias = *(const float4*)&b[o0];
#pragma unroll
    for (int i = 0; i < 4; i++) {
        int n = nodeBase + n0 + i;
        if (n < N_NODES) {
            float vx = fmaxf(c[i][0] + bias.x, 0.f);
            float vy = fmaxf(c[i][1] + bias.y, 0.f);
            float vz = fmaxf(c[i][2] + bias.z, 0.f);
            float vw = fmaxf(c[i][3] + bias.w, 0.f);
            store_h4(&h016[(size_t)n * NHID + o0], vx, vy, vz, vw);
            float dn = dinv[n];
            store_h4(&hs1[(size_t)n * NHID + o0], vx * dn, vy * dn, vz * dn, vw * dn);
        }
    }
}

// ------- fused GCN2Conv layer: WAVE-AUTONOMOUS (no __syncthreads) -------
// Each wave owns 8 nodes: stages its own metas (per-wave LDS slab, lgkm-fenced),
// walks edges with the 2-deep copy->refill->FMA pipeline (R1-proven; FMA-first
// created a register WAR that delayed load issue -> R2 regression), writes mix
// to its private slab, fences, and does its own 8x64 GEMM. No block barrier ->
// no coupling to the block's max-degree tail (max of 8 Poisson(16) draws ~26
// vs 32 draws ~30), no staging barrier drain.

__global__ __launch_bounds__(256, 4) void k_conv(const __half* __restrict__ hs,
                                                 const __half* __restrict__ h0,
                                                 const int* __restrict__ rowptr,
                                                 const int* __restrict__ e4,
                                                 const float* __restrict__ W,   // [c][o] 64x64
                                                 const float* __restrict__ dinv,
                                                 __half* __restrict__ hout,
                                                 int scaled) {
    __shared__ int   eSw[4][WECAP];
    __shared__ float mixs[4][8 * 68];
    int t = threadIdx.x;
    int wid = t >> 6, lane = t & 63;
    int wbase = blockIdx.x * 32 + wid * 8;   // 8 nodes per wave; N_NODES % 32 == 0
    int grp = lane >> 3;                     // 8 groups of 8 lanes -> 1 node each
    int cg = (lane & 7) * 8;                 // 8 channels per lane
    int* eW = eSw[wid];
    float* mix = mixs[wid];

    int n = wbase + grp;
    int s = rowptr[n], e = rowptr[n + 1];
    int wb0 = rowptr[wbase];
    int wbN = rowptr[wbase + 8] - wb0;
    int nStage = (wbN < WECAP) ? wbN : WECAP;
    for (int i = lane; i < nStage; i += 64) eW[i] = e4[wb0 + i];

#define LOADM_G(pm, jb)                                                  \
    {                                                                    \
        _Pragma("unroll")                                                \
        for (int u = 0; u < 4; u++) {                                    \
            int idx = (jb) + u;                                          \
            pm[u] = (idx < e) ? e4[idx] : N_NODES;                       \
        }                                                                \
    }
#define LOADM(pm, jb)                                                    \
    {                                                                    \
        _Pragma("unroll")                                                \
        for (int u = 0; u < 4; u++) {                                    \
            int idx = (jb) + u;                                          \
            int m = N_NODES;                                             \
            if (idx < e) {                                               \
                int li = idx - wb0;                                      \
                m = (li < WECAP) ? eW[li] : e4[idx];                     \
            }                                                            \
            pm[u] = m;                                                   \
        }                                                                \
    }
#define ISSUE(pv, pm)                                                    \
    {                                                                    \
        _Pragma("unroll")                                                \
        for (int u = 0; u < 4; u++)                                      \
            pv[u] = *(const float4*)&hs[(size_t)pm[u] * NHID + cg];      \
    }
#define ACC4(cv)                                                         \
    {                                                                    \
        _Pragma("unroll")                                                \
        for (int u = 0; u < 4; u++) {                                    \
            const __half2* hp = (const __half2*)&cv[u];                  \
            _Pragma("unroll")                                            \
            for (int q = 0; q < 4; q++) {                                \
                float2 f = __half22float2(hp[q]);                       \
                acc[q * 2 + 0] += f.x;                                   \
                acc[q * 2 + 1] += f.y;                                   \
            }                                                            \
        }                                                                \
    }

    // prologue from global: independent of the eW staging
    int    pmA[4], pmB[4];
    float4 pvA[4], pvB[4];
    LOADM_G(pmA, s);     ISSUE(pvA, pmA);
    LOADM_G(pmB, s + 4); ISSUE(pvB, pmB);

    float dn = dinv[n];
    float4 h0raw = *(const float4*)&h0[(size_t)n * NHID + cg];   // 8 halves

    float acc[8];
#pragma unroll
    for (int i = 0; i < 8; i++) acc[i] = 0.f;

    __threadfence_block();   // eW visible to all lanes of this wave (lgkm drain, no barrier)

    for (int j = s; j < e; j += 8) {
        {
            float4 cv[4];
#pragma unroll
            for (int u = 0; u < 4; u++) cv[u] = pvA[u];
            int jn = j + 8;
            if (jn < e) { LOADM(pmA, jn); ISSUE(pvA, pmA); }
            ACC4(cv);
        }
        if (j + 4 < e) {
            float4 cv[4];
#pragma unroll
            for (int u = 0; u < 4; u++) cv[u] = pvB[u];
            int jn = j + 12;
            if (jn < e) { LOADM(pmB, jn); ISSUE(pvB, pmB); }
            ACC4(cv);
        }
    }
#undef LOADM_G
#undef LOADM
#undef ISSUE
#undef ACC4

    {
        const __half* h0h = (const __half*)&h0raw;
        float a = 0.9f * dn;
        float m[8];
#pragma unroll
        for (int q = 0; q < 8; q++)
            m[q] = fmaf(a, acc[q], 0.1f * __half2float(h0h[q]));
        float4 m0 = {m[0], m[1], m[2], m[3]};
        float4 m1 = {m[4], m[5], m[6], m[7]};
        *(float4*)&mix[grp * 68 + cg] = m0;
        *(float4*)&mix[grp * 68 + cg + 4] = m1;
    }
    __threadfence_block();   // mix visible within wave

    // per-wave GEMM 8x64, 2x4 acc per lane; W rows broadcast via L1; fp16 output
    int tx = lane & 15, ty = lane >> 4;
    int o0 = tx * 4, r0 = ty * 2;
    float c[2][4];
#pragma unroll
    for (int i = 0; i < 2; i++)
#pragma unroll
        for (int j = 0; j < 4; j++) c[i][j] = 0.f;

#pragma unroll 4
    for (int k = 0; k < NHID; k += 4) {
        float4 b0 = *(const float4*)&W[(k + 0) * NHID + o0];
        float4 b1 = *(const float4*)&W[(k + 1) * NHID + o0];
        float4 b2 = *(const float4*)&W[(k + 2) * NHID + o0];
        float4 b3 = *(const float4*)&W[(k + 3) * NHID + o0];
#pragma unroll
        for (int i = 0; i < 2; i++) {
            float4 a = *(const float4*)&mix[(r0 + i) * 68 + k];
            c[i][0] = fmaf(a.x, b0.x, fmaf(a.y, b1.x, fmaf(a.z, b2.x, fmaf(a.w, b3.x, c[i][0]))));
            c[i][1] = fmaf(a.x, b0.y, fmaf(a.y, b1.y, fmaf(a.z, b2.y, fmaf(a.w, b3.y, c[i][1]))));
            c[i][2] = fmaf(a.x, b0.z, fmaf(a.y, b1.z, fmaf(a.z, b2.z, fmaf(a.w, b3.z, c[i][2]))));
            c[i][3] = fmaf(a.x, b0.w, fmaf(a.y, b1.w, fmaf(a.z, b2.w, fmaf(a.w, b3.w, c[i][3]))));
        }
    }
#pragma unroll
    for (int i = 0; i < 2; i++) {
        int n2 = wbase + r0 + i;
        float sc = 1.0f;
        if (scaled) sc = dinv[n2];
        store_h4(&hout[(size_t)n2 * NHID + o0],
                 fmaxf(c[i][0], 0.f) * sc, fmaxf(c[i][1], 0.f) * sc,
                 fmaxf(c[i][2], 0.f) * sc, fmaxf(c[i][3], 0.f) * sc);
    }
}

// ---------------- fc2: out = h @ fc2_w^T + b (h in fp16) ----------------

__global__ __launch_bounds__(256) void k_fc2(const __half* __restrict__ h,
                                             const float* __restrict__ w,
                                             const float* __restrict__ b,
                                             float* __restrict__ out) {
    __shared__ float wT[NHID * 44];
    __shared__ float hsl[64 * 68];
    int t = threadIdx.x;
    int nodeBase = blockIdx.x * 64;

    for (int id = t; id < NHID * OUT_CH; id += 256) {
        int o = id >> 6, k = id & 63;
        wT[k * 44 + o] = w[id];
    }
    {
        int nl = t >> 2, seg = t & 3;
        int n = nodeBase + nl;
        float* dst = hsl + nl * 68 + seg * 16;
        if (n < N_NODES) {
            float4 raw0 = *(const float4*)&h[(size_t)n * NHID + seg * 16];
            float4 raw1 = *(const float4*)&h[(size_t)n * NHID + seg * 16 + 8];
            const __half2* hp0 = (const __half2*)&raw0;
            const __half2* hp1 = (const __half2*)&raw1;
#pragma unroll
            for (int q = 0; q < 4; q++) {
                float2 f = __half22float2(hp0[q]);
                dst[q * 2 + 0] = f.x;
                dst[q * 2 + 1] = f.y;
            }
#pragma unroll
            for (int q = 0; q < 4; q++) {
                float2 f = __half22float2(hp1[q]);
                dst[8 + q * 2 + 0] = f.x;
                dst[8 + q * 2 + 1] = f.y;
            }
        } else {
#pragma unroll
            for (int q = 0; q < 16; q++) dst[q] = 0.f;
        }
    }
    __syncthreads();

    if (t < 160) {
        int tx = t % 10, ty = t / 10;
        int o0 = tx * 4, n0 = ty * 4;
        float c[4][4];
#pragma unroll
        for (int i = 0; i < 4; i++)
#pragma unroll
            for (int j = 0; j < 4; j++) c[i][j] = 0.f;

#pragma unroll 4
        for (int k = 0; k < NHID; k += 4) {
            float4 b0 = *(const float4*)&wT[(k + 0) * 44 + o0];
            float4 b1 = *(const float4*)&wT[(k + 1) * 44 + o0];
            float4 b2 = *(const float4*)&wT[(k + 2) * 44 + o0];
            float4 b3 = *(const float4*)&wT[(k + 3) * 44 + o0];
#pragma unroll
            for (int i = 0; i < 4; i++) {
                float4 a = *(const float4*)&hsl[(n0 + i) * 68 + k];
                c[i][0] = fmaf(a.x, b0.x, fmaf(a.y, b1.x, fmaf(a.z, b2.x, fmaf(a.w, b3.x, c[i][0]))));
                c[i][1] = fmaf(a.x, b0.y, fmaf(a.y, b1.y, fmaf(a.z, b2.y, fmaf(a.w, b3.y, c[i][1]))));
                c[i][2] = fmaf(a.x, b0.z, fmaf(a.y, b1.z, fmaf(a.z, b2.z, fmaf(a.w, b3.z, c[i][2]))));
                c[i][3] = fmaf(a.x, b0.w, fmaf(a.y, b1.w, fmaf(a.z, b2.w, fmaf(a.w, b3.w, c[i][3]))));
            }
        }
        float4 bias = *(const float4*)&b[o0];
#pragma unroll
        for (int i = 0; i < 4; i++) {
            int n = nodeBase + n0 + i;
            if (n < N_NODES) {
                float4 v;
                v.x = c[i][0] + bias.x;
                v.y = c[i][1] + bias.y;
                v.z = c[i][2] + bias.z;
                v.w = c[i][3] + bias.w;
                *(float4*)&out[(size_t)n * OUT_CH + o0] = v;
            }
        }
    }
}

// ---------------- launch ----------------

extern "C" void kernel_launch(void* const* d_in, const int* in_sizes, int n_in,
                              void* d_out, int out_size, void* d_ws, size_t ws_size,
                              hipStream_t stream) {
    const float* x    = (const float*)d_in[0];
    const int*   ei   = (const int*)d_in[1];
    const float* fc1w = (const float*)d_in[3];
    const float* fc1b = (const float*)d_in[4];
    const float* cw   = (const float*)d_in[5];
    const float* fc2w = (const float*)d_in[6];
    const float* fc2b = (const float*)d_in[7];
    float* out = (float*)d_out;

    char* p = (char*)d_ws;
    auto alloc = [&](size_t bytes) { char* r = p; p += (bytes + 255) & ~(size_t)255; return r; };
    __half* h016   = (__half*)alloc((size_t)N_NODES * NHID * 2);
    __half* hsA    = (__half*)alloc((size_t)(N_NODES + 1) * NHID * 2);   // +1 zero row
    __half* hsB    = (__half*)alloc((size_t)(N_NODES + 1) * NHID * 2);   // +1 zero row
    int*    e4     = (int*)   alloc((size_t)(N_EDGES + 8) * 4);
    int2*   ebufA  = (int2*)  alloc((size_t)NBUCK * BCAP * 8);   // 14.05 MB; reused as h4 buffer
    int*    cnt    = (int*)   alloc((size_t)N_NODES * 4);
    int*    rowptr = (int*)   alloc((size_t)(N_NODES + 1) * 4);
    int*    bCnt   = (int*)   alloc((size_t)NBUCK * 4);
    float*  dinv   = (float*) alloc((size_t)N_NODES * 4);
    int*    bsum   = (int*)   alloc(512 * 4);
    __half* h4     = (__half*)ebufA;    // layer-4 unscaled output (after scatB consumed ebufA)

    hipMemsetAsync(bCnt, 0, (size_t)NBUCK * 4, stream);
    hipMemsetAsync(cnt, 0, (size_t)N_NODES * 4, stream);
    hipMemsetAsync(hsA + (size_t)N_NODES * NHID, 0, NHID * 2, stream);
    hipMemsetAsync(hsB + (size_t)N_NODES * NHID, 0, NHID * 2, stream);

    k_scatA<<<(N_EDGES + 4095) / 4096, 256, 0, stream>>>(ei, bCnt, ebufA, cnt);
    k_scan1<<<NBLK, 256, 0, stream>>>(cnt, rowptr, bsum, dinv);
    k_scan2<<<1, 512, 0, stream>>>(bsum);
    k_scan3<<<NBLK, 256, 0, stream>>>(bsum, rowptr);
    k_scatB<<<NBUCK, 256, 0, stream>>>(ebufA, bCnt, rowptr, e4);

    int gb64 = (N_NODES + 63) / 64;   // 1563
    int gb32 = N_NODES / 32;          // 3125
    k_fc1 <<<gb64, 256, 0, stream>>>(x, fc1w, fc1b, dinv, h016, hsA);
    k_conv<<<gb32, 256, 0, stream>>>(hsA, h016, rowptr, e4, cw + 0 * NHID * NHID, dinv, hsB, 1);
    k_conv<<<gb32, 256, 0, stream>>>(hsB, h016, rowptr, e4, cw + 1 * NHID * NHID, dinv, hsA, 1);
    k_conv<<<gb32, 256, 0, stream>>>(hsA, h016, rowptr, e4, cw + 2 * NHID * NHID, dinv, hsB, 1);
    k_conv<<<gb32, 256, 0, stream>>>(hsB, h016, rowptr, e4, cw + 3 * NHID * NHID, dinv, h4, 0);
    k_fc2 <<<gb64, 256, 0, stream>>>(h4, fc2w, fc2b, out);
}

// Round 7
// 409.874 us; speedup vs baseline: 1.1369x; 1.1369x over previous
//
#include <hip/hip_runtime.h>
#include <hip/hip_fp16.h>

#define N_NODES 100000
#define N_EDGES 1600000
#define IN_CH   128
#define NHID    64
#define OUT_CH  40
#define NBLK    391    // ceil(N_NODES/256)
#define NBUCK   196    // ceil(N_NODES/512)
#define BCAP    8960   // fixed bucket capacity (mean 8163, +8 sigma)
#define WECAP   320    // per-WAVE padded edge stage (8 nodes: mean ~160, +12 sigma; overflow -> global fallback)
#define E4CAP   (N_EDGES + 7 * N_NODES + 64)   // padded CSR worst case

// ---------------- rowptr scans (over PADDED counts; dinv from true counts) ----------------

__global__ __launch_bounds__(256) void k_scan1(const int* __restrict__ cnt,
                                               int* __restrict__ rowptr,
                                               int* __restrict__ bsum,
                                               float* __restrict__ dinv) {
    __shared__ int s[256];
    int t = threadIdx.x;
    int n = blockIdx.x * 256 + t;
    int v = (n < N_NODES) ? cnt[n] : 0;
    int pv = (v + 7) & ~7;                  // pad to multiple of 8
    s[t] = pv;
    __syncthreads();
    for (int off = 1; off < 256; off <<= 1) {
        int add = (t >= off) ? s[t - off] : 0;
        __syncthreads();
        s[t] += add;
        __syncthreads();
    }
    int incl = s[t];
    if (n < N_NODES) {
        rowptr[n] = incl - pv;
        dinv[n] = (v > 0) ? rsqrtf((float)v) : 0.0f;
    }
    if (t == 255) bsum[blockIdx.x] = incl;
}

__global__ __launch_bounds__(512) void k_scan2(int* __restrict__ bsum,
                                               int* __restrict__ rowptr) {
    __shared__ int s[512];
    int t = threadIdx.x;
    int v = (t < NBLK) ? bsum[t] : 0;
    s[t] = v;
    __syncthreads();
    for (int off = 1; off < 512; off <<= 1) {
        int add = (t >= off) ? s[t - off] : 0;
        __syncthreads();
        s[t] += add;
        __syncthreads();
    }
    if (t == NBLK - 1) rowptr[N_NODES] = s[t];   // padded grand total
    if (t < NBLK) bsum[t] = s[t] - v;
}

__global__ __launch_bounds__(256) void k_scan3(const int* __restrict__ bsum,
                                               int* __restrict__ rowptr) {
    int n = blockIdx.x * 256 + threadIdx.x;
    if (n < N_NODES) rowptr[n] = rowptr[n] + bsum[n >> 8];
}

// ---- scatter pass A: fixed-capacity buckets by c>>9 (pure bucketing; R5-proven) ----

__global__ __launch_bounds__(256) void k_scatA(const int* __restrict__ ei,
                                               int* __restrict__ bucketCnt,
                                               int2* __restrict__ ebufA) {
    __shared__ int hist[NBUCK];
    __shared__ int base[NBUCK];
    int t = threadIdx.x;
    int chunk = blockIdx.x * 4096;
    for (int i = t; i < NBUCK; i += 256) hist[i] = 0;
    __syncthreads();
#pragma unroll 4
    for (int i = 0; i < 16; i++) {
        int e = chunk + i * 256 + t;
        if (e < N_EDGES) atomicAdd(&hist[ei[N_EDGES + e] >> 9], 1);
    }
    __syncthreads();
    for (int b = t; b < NBUCK; b += 256) {
        int h = hist[b];
        base[b] = h ? atomicAdd(&bucketCnt[b], h) : 0;
    }
    __syncthreads();
#pragma unroll 4
    for (int i = 0; i < 16; i++) {
        int e = chunk + i * 256 + t;
        if (e < N_EDGES) {
            int r = ei[e], c = ei[N_EDGES + e];
            int pos = atomicAdd(&base[c >> 9], 1);
            ebufA[(size_t)(c >> 9) * BCAP + pos] = make_int2(r, c);
        }
    }
}

// ---- degree count from bucketed edges: contiguous read, LDS histogram (restored) ----

__global__ __launch_bounds__(256) void k_deg(const int2* __restrict__ ebufA,
                                             const int* __restrict__ bucketCnt,
                                             int* __restrict__ cnt) {
    __shared__ int hist[512];
    int b = blockIdx.x;
    int nodeB = b * 512;
    int t = threadIdx.x;
    for (int i = t; i < 512; i += 256) hist[i] = 0;
    __syncthreads();
    int nE = bucketCnt[b];
    const int2* src = ebufA + (size_t)b * BCAP;
    for (int i = t; i < nE; i += 256) atomicAdd(&hist[src[i].y - nodeB], 1);
    __syncthreads();
    for (int i = t; i < 512; i += 256) {
        int node = nodeB + i;
        if (node < N_NODES) cnt[node] = hist[i];
    }
}

// ---- scatter pass B: per-NODE cursors -> padded CSR; tail-fill pads with zero row ----

__global__ __launch_bounds__(256) void k_scatB(const int2* __restrict__ ebufA,
                                               const int* __restrict__ bucketCnt,
                                               const int* __restrict__ rowptr,
                                               int* __restrict__ e4) {
    __shared__ int lcur[512];
    int b = blockIdx.x;
    int nodeB = b * 512;
    int t = threadIdx.x;
    for (int i = t; i < 512; i += 256) {
        int node = nodeB + i;
        lcur[i] = (node < N_NODES) ? rowptr[node] : 0;
    }
    __syncthreads();
    int nE = bucketCnt[b];
    const int2* src = ebufA + (size_t)b * BCAP;
    for (int i = t; i < nE; i += 256) {
        int2 rc = src[i];
        int pos = atomicAdd(&lcur[rc.y - nodeB], 1);
        e4[pos] = rc.x;
    }
    __syncthreads();
    // pad each node's list to its padded end with the zero row (<=7 per node)
    for (int i = t; i < 512; i += 256) {
        int node = nodeB + i;
        if (node < N_NODES) {
            int end = rowptr[node + 1];
            for (int pos = lcur[i]; pos < end; pos++) e4[pos] = N_NODES;
        }
    }
}

// ---- pack 4 floats -> 4 halves (8B) ----
__device__ __forceinline__ void store_h4(__half* dst, float a, float b, float c, float d) {
    union { uint2 u; __half2 h[2]; } pk;
    pk.h[0] = __floats2half2_rn(a, b);
    pk.h[1] = __floats2half2_rn(c, d);
    *(uint2*)dst = pk.u;
}

// ---------------- fc1: retiled (nodes on ty, channels on tx) + W in LDS ----------------
// Stores are 4 full 128B rows per instruction (no partial-line write amplification).
// W staged in LDS with the same XOR swizzle; compute reads are <=2-way (free).

__global__ __launch_bounds__(256, 2) void k_fc1(const float* __restrict__ x,
                                                const float* __restrict__ w,
                                                const float* __restrict__ b,
                                                const float* __restrict__ dinv,
                                                __half* __restrict__ h016,
                                                __half* __restrict__ hs1) {
    __shared__ float xs[64 * 128];     // [node row][f4idx ^ swz]
    __shared__ float wL[64 * 128];     // [out ch row][f4idx ^ swz]
    int t = threadIdx.x;
    int nodeBase = blockIdx.x * 64;

    {
        int lane8 = t & 7, rhalf = t >> 3;     // 32 rows per pass
#pragma unroll
        for (int r2 = 0; r2 < 2; r2++) {
            int nl = r2 * 32 + rhalf;
            int swz = (nl ^ (nl >> 3)) & 7;
            int n = nodeBase + nl;
            float4* dstrow = (float4*)(xs + nl * 128);
            if (n < N_NODES) {
                const float4* src = (const float4*)(x + (size_t)n * IN_CH);
#pragma unroll
                for (int q = 0; q < 4; q++) dstrow[(q * 8 + lane8) ^ swz] = src[q * 8 + lane8];
            } else {
                float4 z = {0.f, 0.f, 0.f, 0.f};
#pragma unroll
                for (int q = 0; q < 4; q++) dstrow[(q * 8 + lane8) ^ swz] = z;
            }
            float4* dstw = (float4*)(wL + nl * 128);
            const float4* srcw = (const float4*)(w + (size_t)nl * IN_CH);
#pragma unroll
            for (int q = 0; q < 4; q++) dstw[(q * 8 + lane8) ^ swz] = srcw[q * 8 + lane8];
        }
    }
    __syncthreads();

    int tx = t & 15, ty = t >> 4;
    int o0 = tx * 4, n0 = ty * 4;     // nodes on ty, channels on tx
    int swzA0 = ((n0 + 0) ^ ((n0 + 0) >> 3)) & 7;
    int swzA1 = ((n0 + 1) ^ ((n0 + 1) >> 3)) & 7;
    int swzA2 = ((n0 + 2) ^ ((n0 + 2) >> 3)) & 7;
    int swzA3 = ((n0 + 3) ^ ((n0 + 3) >> 3)) & 7;
    int swzW0 = ((o0 + 0) ^ ((o0 + 0) >> 3)) & 7;
    int swzW1 = ((o0 + 1) ^ ((o0 + 1) >> 3)) & 7;
    int swzW2 = ((o0 + 2) ^ ((o0 + 2) >> 3)) & 7;
    int swzW3 = ((o0 + 3) ^ ((o0 + 3) >> 3)) & 7;
    const float4* ar0 = (const float4*)(xs + (n0 + 0) * 128);
    const float4* ar1 = (const float4*)(xs + (n0 + 1) * 128);
    const float4* ar2 = (const float4*)(xs + (n0 + 2) * 128);
    const float4* ar3 = (const float4*)(xs + (n0 + 3) * 128);
    const float4* wr0 = (const float4*)(wL + (o0 + 0) * 128);
    const float4* wr1 = (const float4*)(wL + (o0 + 1) * 128);
    const float4* wr2 = (const float4*)(wL + (o0 + 2) * 128);
    const float4* wr3 = (const float4*)(wL + (o0 + 3) * 128);

    float c[4][4];
#pragma unroll
    for (int i = 0; i < 4; i++)
#pragma unroll
        for (int j = 0; j < 4; j++) c[i][j] = 0.f;

#pragma unroll 4
    for (int k = 0; k < IN_CH; k += 4) {
        int kk = k >> 2;
        float4 b0 = wr0[kk ^ swzW0];
        float4 b1 = wr1[kk ^ swzW1];
        float4 b2 = wr2[kk ^ swzW2];
        float4 b3 = wr3[kk ^ swzW3];
        float4 a0 = ar0[kk ^ swzA0];
        float4 a1 = ar1[kk ^ swzA1];
        float4 a2 = ar2[kk ^ swzA2];
        float4 a3 = ar3[kk ^ swzA3];
#pragma unroll
        for (int i = 0; i < 4; i++) {
            float4 a = (i == 0) ? a0 : (i == 1) ? a1 : (i == 2) ? a2 : a3;
            c[i][0] = fmaf(a.x, b0.x, fmaf(a.y, b0.y, fmaf(a.z, b0.z, fmaf(a.w, b0.w, c[i][0]))));
            c[i][1] = fmaf(a.x, b1.x, fmaf(a.y, b1.y, fmaf(a.z, b1.z, fmaf(a.w, b1.w, c[i][1]))));
            c[i][2] = fmaf(a.x, b2.x, fmaf(a.y, b2.y, fmaf(a.z, b2.z, fmaf(a.w, b2.w, c[i][2]))));
            c[i][3] = fmaf(a.x, b3.x, fmaf(a.y, b3.y, fmaf(a.z, b3.z, fmaf(a.w, b3.w, c[i][3]))));
        }
    }

    float4 bias = *(const float4*)&b[o0];
#pragma unroll
    for (int i = 0; i < 4; i++) {
        int n = nodeBase + n0 + i;
        if (n < N_NODES) {
            float vx = fmaxf(c[i][0] + bias.x, 0.f);
            float vy = fmaxf(c[i][1] + bias.y, 0.f);
            float vz = fmaxf(c[i][2] + bias.z, 0.f);
            float vw = fmaxf(c[i][3] + bias.w, 0.f);
            store_h4(&h016[(size_t)n * NHID + o0], vx, vy, vz, vw);
            float dn = dinv[n];
            store_h4(&hs1[(size_t)n * NHID + o0], vx * dn, vy * dn, vz * dn, vw * dn);
        }
    }
}

// ------- fused GCN2Conv layer: wave-autonomous, PADDED branch-free edge walk -------
// Degrees are padded to multiples of 8 (pad entries = zero row, L1-hot), so the
// inner loop has no per-edge bounds logic: LOADM is a pure LDS read (+cap select),
// both batches unconditional. 2-deep copy->refill->FMA pipeline (R1-proven order).

__global__ __launch_bounds__(256, 4) void k_conv(const __half* __restrict__ hs,
                                                 const __half* __restrict__ h0,
                                                 const int* __restrict__ rowptr,
                                                 const int* __restrict__ e4,
                                                 const float* __restrict__ W,   // [c][o] 64x64
                                                 const float* __restrict__ dinv,
                                                 __half* __restrict__ hout,
                                                 int scaled) {
    __shared__ int   eSw[4][WECAP];
    __shared__ float mixs[4][8 * 68];
    int t = threadIdx.x;
    int wid = t >> 6, lane = t & 63;
    int wbase = blockIdx.x * 32 + wid * 8;   // 8 nodes per wave; N_NODES % 32 == 0
    int grp = lane >> 3;                     // 8 groups of 8 lanes -> 1 node each
    int cg = (lane & 7) * 8;                 // 8 channels per lane
    int* eW = eSw[wid];
    float* mix = mixs[wid];

    int n = wbase + grp;
    int s = rowptr[n], e = rowptr[n + 1];    // e-s is a multiple of 8
    int wb0 = rowptr[wbase];
    int wbN = rowptr[wbase + 8] - wb0;
    int nStage = (wbN < WECAP) ? wbN : WECAP;
    for (int i = lane; i < nStage; i += 64) eW[i] = e4[wb0 + i];

#define LOADM(pm, jb)                                                    \
    {                                                                    \
        _Pragma("unroll")                                                \
        for (int u = 0; u < 4; u++) {                                    \
            int idx = (jb) + u;                                          \
            int li = idx - wb0;                                          \
            pm[u] = (li < WECAP) ? eW[li] : e4[idx];                     \
        }                                                                \
    }
#define ISSUE(pv, pm)                                                    \
    {                                                                    \
        _Pragma("unroll")                                                \
        for (int u = 0; u < 4; u++)                                      \
            pv[u] = *(const float4*)&hs[(size_t)pm[u] * NHID + cg];      \
    }
#define ACC4(cv)                                                         \
    {                                                                    \
        _Pragma("unroll")                                                \
        for (int u = 0; u < 4; u++) {                                    \
            const __half2* hp = (const __half2*)&cv[u];                  \
            _Pragma("unroll")                                            \
            for (int q = 0; q < 4; q++) {                                \
                float2 f = __half22float2(hp[q]);                        \
                acc[q * 2 + 0] += f.x;                                   \
                acc[q * 2 + 1] += f.y;                                   \
            }                                                            \
        }                                                                \
    }

    // prologue from global: independent of the eW staging; deg>=8 when nonzero
    int    pmA[4], pmB[4];
    float4 pvA[4], pvB[4];
    if (e > s) {
#pragma unroll
        for (int u = 0; u < 4; u++) pmA[u] = e4[s + u];
        ISSUE(pvA, pmA);
#pragma unroll
        for (int u = 0; u < 4; u++) pmB[u] = e4[s + 4 + u];
        ISSUE(pvB, pmB);
    }

    float dn = dinv[n];
    float4 h0raw = *(const float4*)&h0[(size_t)n * NHID + cg];   // 8 halves

    float acc[8];
#pragma unroll
    for (int i = 0; i < 8; i++) acc[i] = 0.f;

    __threadfence_block();   // eW visible within wave (lgkm drain, no barrier)

    for (int j = s; j < e; j += 8) {
        {
            float4 cv[4];
#pragma unroll
            for (int u = 0; u < 4; u++) cv[u] = pvA[u];
            int jn = j + 8;
            if (jn < e) { LOADM(pmA, jn); ISSUE(pvA, pmA); }
            ACC4(cv);
        }
        {
            float4 cv[4];
#pragma unroll
            for (int u = 0; u < 4; u++) cv[u] = pvB[u];
            int jn = j + 12;
            if (jn < e) { LOADM(pmB, jn); ISSUE(pvB, pmB); }
            ACC4(cv);
        }
    }
#undef LOADM
#undef ISSUE
#undef ACC4

    {
        const __half* h0h = (const __half*)&h0raw;
        float a = 0.9f * dn;
        float m[8];
#pragma unroll
        for (int q = 0; q < 8; q++)
            m[q] = fmaf(a, acc[q], 0.1f * __half2float(h0h[q]));
        float4 m0 = {m[0], m[1], m[2], m[3]};
        float4 m1 = {m[4], m[5], m[6], m[7]};
        *(float4*)&mix[grp * 68 + cg] = m0;
        *(float4*)&mix[grp * 68 + cg + 4] = m1;
    }
    __threadfence_block();   // mix visible within wave

    // per-wave GEMM 8x64, 2x4 acc per lane; W rows broadcast via L1; fp16 output
    int tx = lane & 15, ty = lane >> 4;
    int o0 = tx * 4, r0 = ty * 2;
    float c[2][4];
#pragma unroll
    for (int i = 0; i < 2; i++)
#pragma unroll
        for (int j = 0; j < 4; j++) c[i][j] = 0.f;

#pragma unroll 4
    for (int k = 0; k < NHID; k += 4) {
        float4 b0 = *(const float4*)&W[(k + 0) * NHID + o0];
        float4 b1 = *(const float4*)&W[(k + 1) * NHID + o0];
        float4 b2 = *(const float4*)&W[(k + 2) * NHID + o0];
        float4 b3 = *(const float4*)&W[(k + 3) * NHID + o0];
#pragma unroll
        for (int i = 0; i < 2; i++) {
            float4 a = *(const float4*)&mix[(r0 + i) * 68 + k];
            c[i][0] = fmaf(a.x, b0.x, fmaf(a.y, b1.x, fmaf(a.z, b2.x, fmaf(a.w, b3.x, c[i][0]))));
            c[i][1] = fmaf(a.x, b0.y, fmaf(a.y, b1.y, fmaf(a.z, b2.y, fmaf(a.w, b3.y, c[i][1]))));
            c[i][2] = fmaf(a.x, b0.z, fmaf(a.y, b1.z, fmaf(a.z, b2.z, fmaf(a.w, b3.z, c[i][2]))));
            c[i][3] = fmaf(a.x, b0.w, fmaf(a.y, b1.w, fmaf(a.z, b2.w, fmaf(a.w, b3.w, c[i][3]))));
        }
    }
#pragma unroll
    for (int i = 0; i < 2; i++) {
        int n2 = wbase + r0 + i;
        float sc = 1.0f;
        if (scaled) sc = dinv[n2];
        store_h4(&hout[(size_t)n2 * NHID + o0],
                 fmaxf(c[i][0], 0.f) * sc, fmaxf(c[i][1], 0.f) * sc,
                 fmaxf(c[i][2], 0.f) * sc, fmaxf(c[i][3], 0.f) * sc);
    }
}

// ---------------- fc2: out = h @ fc2_w^T + b (h in fp16) ----------------

__global__ __launch_bounds__(256) void k_fc2(const __half* __restrict__ h,
                                             const float* __restrict__ w,
                                             const float* __restrict__ b,
                                             float* __restrict__ out) {
    __shared__ float wT[NHID * 44];
    __shared__ float hsl[64 * 68];
    int t = threadIdx.x;
    int nodeBase = blockIdx.x * 64;

    for (int id = t; id < NHID * OUT_CH; id += 256) {
        int o = id >> 6, k = id & 63;
        wT[k * 44 + o] = w[id];
    }
    {
        int nl = t >> 2, seg = t & 3;
        int n = nodeBase + nl;
        float* dst = hsl + nl * 68 + seg * 16;
        if (n < N_NODES) {
            float4 raw0 = *(const float4*)&h[(size_t)n * NHID + seg * 16];
            float4 raw1 = *(const float4*)&h[(size_t)n * NHID + seg * 16 + 8];
            const __half2* hp0 = (const __half2*)&raw0;
            const __half2* hp1 = (const __half2*)&raw1;
#pragma unroll
            for (int q = 0; q < 4; q++) {
                float2 f = __half22float2(hp0[q]);
                dst[q * 2 + 0] = f.x;
                dst[q * 2 + 1] = f.y;
            }
#pragma unroll
            for (int q = 0; q < 4; q++) {
                float2 f = __half22float2(hp1[q]);
                dst[8 + q * 2 + 0] = f.x;
                dst[8 + q * 2 + 1] = f.y;
            }
        } else {
#pragma unroll
            for (int q = 0; q < 16; q++) dst[q] = 0.f;
        }
    }
    __syncthreads();

    if (t < 160) {
        int tx = t % 10, ty = t / 10;
        int o0 = tx * 4, n0 = ty * 4;
        float c[4][4];
#pragma unroll
        for (int i = 0; i < 4; i++)
#pragma unroll
            for (int j = 0; j < 4; j++) c[i][j] = 0.f;

#pragma unroll 4
        for (int k = 0; k < NHID; k += 4) {
            float4 b0 = *(const float4*)&wT[(k + 0) * 44 + o0];
            float4 b1 = *(const float4*)&wT[(k + 1) * 44 + o0];
            float4 b2 = *(const float4*)&wT[(k + 2) * 44 + o0];
            float4 b3 = *(const float4*)&wT[(k + 3) * 44 + o0];
#pragma unroll
            for (int i = 0; i < 4; i++) {
                float4 a = *(const float4*)&hsl[(n0 + i) * 68 + k];
                c[i][0] = fmaf(a.x, b0.x, fmaf(a.y, b1.x, fmaf(a.z, b2.x, fmaf(a.w, b3.x, c[i][0]))));
                c[i][1] = fmaf(a.x, b0.y, fmaf(a.y, b1.y, fmaf(a.z, b2.y, fmaf(a.w, b3.y, c[i][1]))));
                c[i][2] = fmaf(a.x, b0.z, fmaf(a.y, b1.z, fmaf(a.z, b2.z, fmaf(a.w, b3.z, c[i][2]))));
                c[i][3] = fmaf(a.x, b0.w, fmaf(a.y, b1.w, fmaf(a.z, b2.w, fmaf(a.w, b3.w, c[i][3]))));
            }
        }
        float4 bias = *(const float4*)&b[o0];
#pragma unroll
        for (int i = 0; i < 4; i++) {
            int n = nodeBase + n0 + i;
            if (n < N_NODES) {
                float4 v;
                v.x = c[i][0] + bias.x;
                v.y = c[i][1] + bias.y;
                v.z = c[i][2] + bias.z;
                v.w = c[i][3] + bias.w;
                *(float4*)&out[(size_t)n * OUT_CH + o0] = v;
            }
        }
    }
}

// ---------------- launch ----------------

extern "C" void kernel_launch(void* const* d_in, const int* in_sizes, int n_in,
                              void* d_out, int out_size, void* d_ws, size_t ws_size,
                              hipStream_t stream) {
    const float* x    = (const float*)d_in[0];
    const int*   ei   = (const int*)d_in[1];
    const float* fc1w = (const float*)d_in[3];
    const float* fc1b = (const float*)d_in[4];
    const float* cw   = (const float*)d_in[5];
    const float* fc2w = (const float*)d_in[6];
    const float* fc2b = (const float*)d_in[7];
    float* out = (float*)d_out;

    char* p = (char*)d_ws;
    auto alloc = [&](size_t bytes) { char* r = p; p += (bytes + 255) & ~(size_t)255; return r; };
    __half* h016   = (__half*)alloc((size_t)N_NODES * NHID * 2);
    __half* hsA    = (__half*)alloc((size_t)(N_NODES + 1) * NHID * 2);   // +1 zero row
    __half* hsB    = (__half*)alloc((size_t)(N_NODES + 1) * NHID * 2);   // +1 zero row
    int*    e4     = (int*)   alloc((size_t)E4CAP * 4);                  // padded CSR
    int2*   ebufA  = (int2*)  alloc((size_t)NBUCK * BCAP * 8);   // 14.05 MB; reused as h4 buffer
    int*    cnt    = (int*)   alloc((size_t)N_NODES * 4);
    int*    rowptr = (int*)   alloc((size_t)(N_NODES + 1) * 4);
    int*    bCnt   = (int*)   alloc((size_t)NBUCK * 4);
    float*  dinv   = (float*) alloc((size_t)N_NODES * 4);
    int*    bsum   = (int*)   alloc(512 * 4);
    __half* h4     = (__half*)ebufA;    // layer-4 unscaled output (after scatB consumed ebufA)

    hipMemsetAsync(bCnt, 0, (size_t)NBUCK * 4, stream);
    hipMemsetAsync(hsA + (size_t)N_NODES * NHID, 0, NHID * 2, stream);
    hipMemsetAsync(hsB + (size_t)N_NODES * NHID, 0, NHID * 2, stream);

    k_scatA<<<(N_EDGES + 4095) / 4096, 256, 0, stream>>>(ei, bCnt, ebufA);
    k_deg  <<<NBUCK, 256, 0, stream>>>(ebufA, bCnt, cnt);
    k_scan1<<<NBLK, 256, 0, stream>>>(cnt, rowptr, bsum, dinv);
    k_scan2<<<1, 512, 0, stream>>>(bsum, rowptr);
    k_scan3<<<NBLK, 256, 0, stream>>>(bsum, rowptr);
    k_scatB<<<NBUCK, 256, 0, stream>>>(ebufA, bCnt, rowptr, e4);

    int gb64 = (N_NODES + 63) / 64;   // 1563
    int gb32 = N_NODES / 32;          // 3125
    k_fc1 <<<gb64, 256, 0, stream>>>(x, fc1w, fc1b, dinv, h016, hsA);
    k_conv<<<gb32, 256, 0, stream>>>(hsA, h016, rowptr, e4, cw + 0 * NHID * NHID, dinv, hsB, 1);
    k_conv<<<gb32, 256, 0, stream>>>(hsB, h016, rowptr, e4, cw + 1 * NHID * NHID, dinv, hsA, 1);
    k_conv<<<gb32, 256, 0, stream>>>(hsA, h016, rowptr, e4, cw + 2 * NHID * NHID, dinv, hsB, 1);
    k_conv<<<gb32, 256, 0, stream>>>(hsB, h016, rowptr, e4, cw + 3 * NHID * NHID, dinv, h4, 0);
    k_fc2 <<<gb64, 256, 0, stream>>>(h4, fc2w, fc2b, out);
}